// Round 17
// baseline (207.061 us; speedup 1.0000x reference)
//
#include <hip/hip_runtime.h>
#include <hip/hip_bf16.h>
#include <math.h>

#define N_TOK 22506
#define LEN   11253

typedef unsigned short u16;
typedef __attribute__((ext_vector_type(8))) short short8;
typedef __attribute__((ext_vector_type(4))) float f32x4;
typedef _Float16 f16x2 __attribute__((ext_vector_type(2)));

#define GLOAD16(g, l) __builtin_amdgcn_global_load_lds( \
    (const __attribute__((address_space(1))) void*)(g), \
    (__attribute__((address_space(3))) void*)(l), 16, 0, 0)

static __device__ __forceinline__ u16 f2bf(float f) {
    unsigned int u = __builtin_bit_cast(unsigned int, f);
    u = (u + 0x7fffu + ((u >> 16) & 1u)) >> 16;
    return (u16)u;
}

// bijective XCD-chunked swizzle (m204)
static __device__ __forceinline__ int xcd_swz(int id, int nwg) {
    int q = nwg >> 3, r = nwg & 7;
    int xcd = id & 7, rank = id >> 3;
    return (xcd < r ? xcd * (q + 1) : r * (q + 1) + (xcd - r) * q) + rank;
}

// ---- weight transposes + bias concat + src/q bf16 conversion, one dispatch ----
__global__ __launch_bounds__(256) void wprep(
    const float* __restrict__ w_value, const float* __restrict__ w_off,
    const float* __restrict__ w_attn, const float* __restrict__ w_out,
    const float* __restrict__ w1, const float* __restrict__ w2,
    const float* __restrict__ b_off, const float* __restrict__ b_attn,
    const float* __restrict__ src, const float* __restrict__ pos,
    u16* __restrict__ wv_t, u16* __restrict__ woa_t, u16* __restrict__ wout_t,
    u16* __restrict__ w1_t, u16* __restrict__ w2_t, float* __restrict__ boa,
    u16* __restrict__ srcb, u16* __restrict__ qb)
{
    int i = blockIdx.x * 256 + threadIdx.x;
    if (i < 65536) {
        wv_t[(i & 255) * 256 + (i >> 8)] = f2bf(w_value[i]);
    } else if (i < 131072) {
        int j = i - 65536;
        woa_t[(j & 255) * 256 + (j >> 8)] = f2bf(w_off[j]);
    } else if (i < 163840) {
        int j = i - 131072;
        woa_t[65536 + (j & 127) * 256 + (j >> 7)] = f2bf(w_attn[j]);
    } else if (i < 229376) {
        int j = i - 163840;
        wout_t[(j & 255) * 256 + (j >> 8)] = f2bf(w_out[j]);
    } else if (i < 491520) {
        int j = i - 229376;
        w1_t[(j & 1023) * 256 + (j >> 10)] = f2bf(w1[j]);
    } else if (i < 753664) {
        int j = i - 491520;
        w2_t[(j & 255) * 1024 + (j >> 8)] = f2bf(w2[j]);
    } else if (i < 754048) {
        int j = i - 753664;
        boa[j] = (j < 256) ? b_off[j] : b_attn[j - 256];
    } else if (i < 754048 + 1440384) {
        int j = i - 754048;                 // float4 index over N_TOK*256
        float4 s = ((const float4*)src)[j];
        float4 p = ((const float4*)pos)[j];
        u16 sb[4] = { f2bf(s.x), f2bf(s.y), f2bf(s.z), f2bf(s.w) };
        u16 q4[4] = { f2bf(s.x + p.x), f2bf(s.y + p.y), f2bf(s.z + p.z), f2bf(s.w + p.w) };
        *(ushort4*)(srcb + (size_t)j * 4) = *(ushort4*)sb;
        *(ushort4*)(qb + (size_t)j * 4) = *(ushort4*)q4;
    }
}

// ============ fused value + off/attn GEMM: 128x128 tile, BK=64, 2-deep ============
// sid%5: p<2 -> value job (out Vh fp16); else off|attn job (out OA f32).
// Conflict-free swizzle: LDS[row][slot] holds global col-slot (slot ^ (row&7)).
__global__ __launch_bounds__(256) void gemm5(
    const u16* __restrict__ srcb, const u16* __restrict__ qb,
    const u16* __restrict__ wv_t, const u16* __restrict__ woa_t,
    const float* __restrict__ b_value, const float* __restrict__ boa,
    u16* __restrict__ Vh, float* __restrict__ OA)
{
    __shared__ u16 As[2 * 8192];   // 2 x 16KB: [r 0..127][k 0..63]
    __shared__ u16 Bs[2 * 8192];
    int tid = threadIdx.x;
    int lane = tid & 63, wid = tid >> 6;
    int wr = wid >> 1, wc = wid & 1;

    int sid = xcd_swz(blockIdx.x, gridDim.x);
    int p = sid % 5, bm = (sid / 5) * 128;
    int job = p < 2 ? 0 : 1;
    int bn = job ? (p - 2) * 128 : p * 128;
    const u16* A  = job ? qb : srcb;
    const u16* Bt = job ? woa_t : wv_t;

    f32x4 acc[4][4] = {};
    int lrow8 = lane >> 3;   // 0..7
    int ss2 = lane & 7;      // 16B slot within row

    auto stage = [&](int t) {
        int k0 = t * 64, sb = t & 1;
        #pragma unroll
        for (int i = 0; i < 4; ++i) {
            int rr = wid * 32 + i * 8 + lrow8;
            int ra = bm + rr; ra = ra < N_TOK ? ra : N_TOK - 1;
            GLOAD16(A + (size_t)ra * 256 + k0 + ((ss2 ^ (rr & 7)) << 3),
                    (char*)As + sb * 16384 + wid * 4096 + i * 1024);
            GLOAD16(Bt + (size_t)(bn + rr) * 256 + k0 + ((ss2 ^ (rr & 7)) << 3),
                    (char*)Bs + sb * 16384 + wid * 4096 + i * 1024);
        }
    };

    stage(0); stage(1);

    int rlo = lane & 15, khalf = lane >> 4;

    for (int t = 0; t < 4; ++t) {
        if (t + 1 < 4) asm volatile("s_waitcnt vmcnt(8)" ::: "memory");
        else           asm volatile("s_waitcnt vmcnt(0)" ::: "memory");
        __builtin_amdgcn_s_barrier();
        __builtin_amdgcn_sched_barrier(0);

        const u16* a_lds = As + (t & 1) * 8192;
        const u16* b_lds = Bs + (t & 1) * 8192;
        short8 af[4][2], bf_[4][2];
        #pragma unroll
        for (int mi = 0; mi < 4; ++mi) {
            int row = wr * 64 + mi * 16 + rlo;
            #pragma unroll
            for (int kk = 0; kk < 2; ++kk)
                af[mi][kk] = *(const short8*)(a_lds + row * 64 + (((khalf + kk * 4) ^ (row & 7)) << 3));
        }
        #pragma unroll
        for (int ni = 0; ni < 4; ++ni) {
            int col = wc * 64 + ni * 16 + rlo;
            #pragma unroll
            for (int kk = 0; kk < 2; ++kk)
                bf_[ni][kk] = *(const short8*)(b_lds + col * 64 + (((khalf + kk * 4) ^ (col & 7)) << 3));
        }

        __builtin_amdgcn_s_setprio(1);
        #pragma unroll
        for (int mi = 0; mi < 4; ++mi)
            #pragma unroll
            for (int ni = 0; ni < 4; ++ni)
                #pragma unroll
                for (int kk = 0; kk < 2; ++kk)
                    acc[mi][ni] = __builtin_amdgcn_mfma_f32_16x16x32_bf16(
                        af[mi][kk], bf_[ni][kk], acc[mi][ni], 0, 0, 0);
        __builtin_amdgcn_s_setprio(0);

        __builtin_amdgcn_sched_barrier(0);
        asm volatile("s_waitcnt lgkmcnt(0)" ::: "memory");
        __builtin_amdgcn_s_barrier();
        if (t + 2 < 4) stage(t + 2);
    }

    int col_l = lane & 15, rgrp = lane >> 4;
    #pragma unroll
    for (int mi = 0; mi < 4; ++mi) {
        #pragma unroll
        for (int j = 0; j < 4; ++j) {
            int row = bm + wr * 64 + mi * 16 + rgrp * 4 + j;
            if (row >= N_TOK) continue;
            #pragma unroll
            for (int ni = 0; ni < 4; ++ni) {
                int col = bn + wc * 64 + ni * 16 + col_l;
                if (job) {
                    OA[(size_t)row * 384 + col] = acc[mi][ni][j] + boa[col];
                } else {
                    _Float16 hv = (_Float16)(acc[mi][ni][j] + b_value[col]);
                    Vh[(size_t)row * 256 + col] = __builtin_bit_cast(u16, hv);
                }
            }
        }
    }
}

// ============ bf16 MFMA GEMM: 128x128 tile, BK=64, 2-deep (FFN1) ============
__global__ __launch_bounds__(256) void gemm2(
    const u16* __restrict__ A, const u16* __restrict__ Bt,
    const float* __restrict__ bias, float* __restrict__ Cf, u16* __restrict__ Cb,
    int M, int Nc, int K, int relu)
{
    __shared__ u16 As[2 * 8192];
    __shared__ u16 Bs[2 * 8192];
    int tid = threadIdx.x;
    int lane = tid & 63, wid = tid >> 6;
    int wr = wid >> 1, wc = wid & 1;

    int nwg = gridDim.x * gridDim.y;
    int sid = xcd_swz(blockIdx.y * gridDim.x + blockIdx.x, nwg);
    int bm = (sid / gridDim.x) * 128, bn = (sid % gridDim.x) * 128;

    f32x4 acc[4][4] = {};
    int lrow8 = lane >> 3;
    int ss2 = lane & 7;

    auto stage = [&](int t) {
        int k0 = t * 64, sb = t & 1;
        #pragma unroll
        for (int i = 0; i < 4; ++i) {
            int rr = wid * 32 + i * 8 + lrow8;
            int ra = bm + rr; ra = ra < M ? ra : M - 1;
            GLOAD16(A + (size_t)ra * K + k0 + ((ss2 ^ (rr & 7)) << 3),
                    (char*)As + sb * 16384 + wid * 4096 + i * 1024);
            GLOAD16(Bt + (size_t)(bn + rr) * K + k0 + ((ss2 ^ (rr & 7)) << 3),
                    (char*)Bs + sb * 16384 + wid * 4096 + i * 1024);
        }
    };

    int KT = K >> 6;
    stage(0); if (KT > 1) stage(1);

    int rlo = lane & 15, khalf = lane >> 4;

    for (int t = 0; t < KT; ++t) {
        if (t + 1 < KT) asm volatile("s_waitcnt vmcnt(8)" ::: "memory");
        else            asm volatile("s_waitcnt vmcnt(0)" ::: "memory");
        __builtin_amdgcn_s_barrier();
        __builtin_amdgcn_sched_barrier(0);

        const u16* a_lds = As + (t & 1) * 8192;
        const u16* b_lds = Bs + (t & 1) * 8192;
        short8 af[4][2], bf_[4][2];
        #pragma unroll
        for (int mi = 0; mi < 4; ++mi) {
            int row = wr * 64 + mi * 16 + rlo;
            #pragma unroll
            for (int kk = 0; kk < 2; ++kk)
                af[mi][kk] = *(const short8*)(a_lds + row * 64 + (((khalf + kk * 4) ^ (row & 7)) << 3));
        }
        #pragma unroll
        for (int ni = 0; ni < 4; ++ni) {
            int col = wc * 64 + ni * 16 + rlo;
            #pragma unroll
            for (int kk = 0; kk < 2; ++kk)
                bf_[ni][kk] = *(const short8*)(b_lds + col * 64 + (((khalf + kk * 4) ^ (col & 7)) << 3));
        }

        __builtin_amdgcn_s_setprio(1);
        #pragma unroll
        for (int mi = 0; mi < 4; ++mi)
            #pragma unroll
            for (int ni = 0; ni < 4; ++ni)
                #pragma unroll
                for (int kk = 0; kk < 2; ++kk)
                    acc[mi][ni] = __builtin_amdgcn_mfma_f32_16x16x32_bf16(
                        af[mi][kk], bf_[ni][kk], acc[mi][ni], 0, 0, 0);
        __builtin_amdgcn_s_setprio(0);

        __builtin_amdgcn_sched_barrier(0);
        asm volatile("s_waitcnt lgkmcnt(0)" ::: "memory");
        __builtin_amdgcn_s_barrier();
        if (t + 2 < KT) stage(t + 2);
    }

    int col_l = lane & 15, rgrp = lane >> 4;
    #pragma unroll
    for (int mi = 0; mi < 4; ++mi) {
        #pragma unroll
        for (int j = 0; j < 4; ++j) {
            int row = bm + wr * 64 + mi * 16 + rgrp * 4 + j;
            if (row >= M) continue;
            #pragma unroll
            for (int ni = 0; ni < 4; ++ni) {
                int col = bn + wc * 64 + ni * 16 + col_l;
                float v = acc[mi][ni][j];
                if (bias) v += bias[col];
                if (relu) v = fmaxf(v, 0.f);
                if (Cf) Cf[(size_t)row * Nc + col] = v;
                if (Cb) Cb[(size_t)row * Nc + col] = f2bf(v);
            }
        }
    }
}

// ============ pipelined Nc=256 GEMM + residual + LayerNorm, BM=64, BK=32, 3-deep ============
__global__ __launch_bounds__(256) void gemm_ln(
    const u16* __restrict__ A, const u16* __restrict__ Bt,
    const float* __restrict__ bias, const float* __restrict__ res,
    const float* __restrict__ g, const float* __restrict__ beta,
    float* __restrict__ outf, u16* __restrict__ outb,
    int M, int K)
{
    __shared__ u16 As[3 * 2048];
    __shared__ u16 Bs[3 * 8192];
    int tid = threadIdx.x;
    int lane = tid & 63, wc = tid >> 6;
    int bm = blockIdx.x * 64;
    f32x4 acc[4][4] = {};
    int srcslot = ((lane & 3) ^ ((lane >> 2) & 3) ^ ((lane >> 4) & 3)) << 3;
    int lrow = lane >> 2;

    auto stage = [&](int t) {
        int k0 = t * 32, sb = t % 3;
        int ra = bm + wc * 16 + lrow; ra = ra < M ? ra : M - 1;
        GLOAD16(A + (size_t)ra * K + k0 + srcslot,
                (char*)As + sb * 4096 + wc * 1024);
        #pragma unroll
        for (int i = 0; i < 4; ++i) {
            int cc = i * 64 + wc * 16 + lrow;
            GLOAD16(Bt + (size_t)cc * K + k0 + srcslot,
                    (char*)Bs + sb * 16384 + i * 4096 + wc * 1024);
        }
    };

    int KT = K >> 5;
    stage(0); stage(1); stage(2);

    int rlo = lane & 15, khalf = lane >> 4;
    int fsl = ((khalf ^ (rlo & 3) ^ ((rlo >> 2) & 3)) << 3);

    for (int t = 0; t < KT; ++t) {
        if (t + 2 < KT)      asm volatile("s_waitcnt vmcnt(10)" ::: "memory");
        else if (t + 1 < KT) asm volatile("s_waitcnt vmcnt(5)" ::: "memory");
        else                 asm volatile("s_waitcnt vmcnt(0)" ::: "memory");
        __builtin_amdgcn_s_barrier();
        __builtin_amdgcn_sched_barrier(0);

        const u16* a_lds = As + (t % 3) * 2048;
        const u16* b_lds = Bs + (t % 3) * 8192;
        short8 af[4], bf_[4];
        #pragma unroll
        for (int mi = 0; mi < 4; ++mi)
            af[mi] = *(const short8*)(a_lds + (mi * 16 + rlo) * 32 + fsl);
        #pragma unroll
        for (int ni = 0; ni < 4; ++ni)
            bf_[ni] = *(const short8*)(b_lds + (wc * 64 + ni * 16 + rlo) * 32 + fsl);

        __builtin_amdgcn_s_setprio(1);
        #pragma unroll
        for (int mi = 0; mi < 4; ++mi)
            #pragma unroll
            for (int ni = 0; ni < 4; ++ni)
                acc[mi][ni] = __builtin_amdgcn_mfma_f32_16x16x32_bf16(
                    af[mi], bf_[ni], acc[mi][ni], 0, 0, 0);
        __builtin_amdgcn_s_setprio(0);

        __builtin_amdgcn_sched_barrier(0);
        asm volatile("s_waitcnt lgkmcnt(0)" ::: "memory");
        __builtin_amdgcn_s_barrier();
        if (t + 3 < KT) stage(t + 3);
    }
    __syncthreads();

    float* red = (float*)As;
    int col_l = lane & 15, rgrp = lane >> 4;
    int colc[4]; float bias_c[4], g_c[4], be_c[4];
    #pragma unroll
    for (int ni = 0; ni < 4; ++ni) {
        colc[ni] = wc * 64 + ni * 16 + col_l;
        bias_c[ni] = bias[colc[ni]];
        g_c[ni]  = g[colc[ni]];
        be_c[ni] = beta[colc[ni]];
    }
    #pragma unroll
    for (int mi = 0; mi < 4; ++mi) {
        #pragma unroll
        for (int j = 0; j < 4; ++j) {
            int rl = mi * 16 + rgrp * 4 + j;
            int row = bm + rl;
            float s = 0.f, s2 = 0.f;
            if (row < M) {
                #pragma unroll
                for (int ni = 0; ni < 4; ++ni) {
                    float v = acc[mi][ni][j] + bias_c[ni] + res[(size_t)row * 256 + colc[ni]];
                    acc[mi][ni][j] = v;
                    s += v; s2 += v * v;
                }
            }
            #pragma unroll
            for (int d = 1; d < 16; d <<= 1) { s += __shfl_xor(s, d); s2 += __shfl_xor(s2, d); }
            if (col_l == 0) { red[wc * 64 + rl] = s; red[256 + wc * 64 + rl] = s2; }
        }
    }
    __syncthreads();
    if (tid < 64) {
        float s  = red[tid] + red[64 + tid] + red[128 + tid] + red[192 + tid];
        float s2 = red[256 + tid] + red[320 + tid] + red[384 + tid] + red[448 + tid];
        float mean = s * (1.f / 256.f);
        float var = s2 * (1.f / 256.f) - mean * mean;
        red[512 + tid] = mean;
        red[576 + tid] = rsqrtf(var + 1e-5f);
    }
    __syncthreads();
    #pragma unroll
    for (int mi = 0; mi < 4; ++mi) {
        #pragma unroll
        for (int j = 0; j < 4; ++j) {
            int rl = mi * 16 + rgrp * 4 + j;
            int row = bm + rl;
            if (row >= M) continue;
            float mean = red[512 + rl], rs = red[576 + rl];
            #pragma unroll
            for (int ni = 0; ni < 4; ++ni) {
                float o = g_c[ni] * (acc[mi][ni][j] - mean) * rs + be_c[ni];
                outf[(size_t)row * 256 + colc[ni]] = o;
                if (outb) outb[(size_t)row * 256 + colc[ni]] = f2bf(o);
            }
        }
    }
}

// ---- deformable sampling: 2 waves/token, fp16 value, packed v_pk_fma_f16 ----
__global__ __launch_bounds__(256) void ms_sample(
    const u16* __restrict__ value, const float* __restrict__ oa,
    const float* __restrict__ refp, u16* __restrict__ out)
{
    const int starts[4] = {0, 8464, 10580, 11109};
    const int sizes[4]  = {92, 46, 23, 12};
    int t = threadIdx.x;
    int wid = t >> 6, lane = t & 63;
    int wv2 = wid >> 1;
    int wpar = wid & 1;
    int n = blockIdx.x * 2 + wv2;   // grid = N_TOK/2 exactly

    __shared__ uint4 s_ad[2][128];
    __shared__ uint4 s_wt[2][128];

    const float* oan = oa + (size_t)n * 384;
    unsigned int tokbase = (n >= LEN) ? (unsigned)LEN : 0u;
    {
        int q = wpar * 64 + lane;         // q = h*16 + pt
        int h = q >> 4, pt = q & 15, l = pt >> 2;
        float logit = oan[256 + q];
        float m = logit;
        #pragma unroll
        for (int d = 1; d < 16; d <<= 1) m = fmaxf(m, __shfl_xor(m, d));
        float e = __expf(logit - m);
        float ssum = e;
        #pragma unroll
        for (int d = 1; d < 16; d <<= 1) ssum += __shfl_xor(ssum, d);
        float aw = e / ssum;
        float2 off2 = *(const float2*)(oan + 2 * q);
        float2 ref2 = *(const float2*)(refp + (size_t)n * 8 + l * 2);
        int wl = sizes[l];
        float wf = (float)wl;
        float x = ref2.x * wf - 0.5f + off2.x;
        float y = ref2.y * wf - 0.5f + off2.y;
        float x0f = floorf(x), y0f = floorf(y);
        float fx = x - x0f, fy = y - y0f;
        int x0 = (int)x0f, y0 = (int)y0f;
        int x1 = x0 + 1, y1 = y0 + 1;
        float gx = 1.f - fx, gy = 1.f - fy;
        bool bx0 = (unsigned)x0 < (unsigned)wl, bx1 = (unsigned)x1 < (unsigned)wl;
        bool by0 = (unsigned)y0 < (unsigned)wl, by1 = (unsigned)y1 < (unsigned)wl;
        float w00 = (bx0 && by0) ? gx * gy * aw : 0.f;
        float w10 = (bx1 && by0) ? fx * gy * aw : 0.f;
        float w01 = (bx0 && by1) ? gx * fy * aw : 0.f;
        float w11 = (bx1 && by1) ? fx * fy * aw : 0.f;
        int x0c = min(max(x0, 0), wl - 1), x1c = min(max(x1, 0), wl - 1);
        int y0c = min(max(y0, 0), wl - 1), y1c = min(max(y1, 0), wl - 1);
        unsigned int base = (tokbase + (unsigned)starts[l]) * 512u + (unsigned)(h * 64);
        unsigned int r0 = base + (unsigned)(y0c * wl) * 512u;
        unsigned int r1 = base + (unsigned)(y1c * wl) * 512u;
        int idx = pt * 8 + (h ^ (pt & 7));
        s_ad[wv2][idx] = make_uint4(r0 + (unsigned)x0c * 512u, r0 + (unsigned)x1c * 512u,
                                    r1 + (unsigned)x0c * 512u, r1 + (unsigned)x1c * 512u);
        s_wt[wv2][idx] = make_uint4(
            __builtin_bit_cast(unsigned int, __builtin_amdgcn_cvt_pkrtz(w00, w00)),
            __builtin_bit_cast(unsigned int, __builtin_amdgcn_cvt_pkrtz(w10, w10)),
            __builtin_bit_cast(unsigned int, __builtin_amdgcn_cvt_pkrtz(w01, w01)),
            __builtin_bit_cast(unsigned int, __builtin_amdgcn_cvt_pkrtz(w11, w11)));
    }
    asm volatile("s_waitcnt lgkmcnt(0)" ::: "memory");

    int h = wpar * 4 + (lane >> 4);
    int dq = lane & 15;
    const char* vb = (const char*)value + dq * 4;

    f16x2 v00[3], v10[3], v01[3], v11[3];
    f16x2 w0[3], w1_[3], w2_[3], w3[3];
    f16x2 c0 = {0, 0}, c1 = {0, 0}, c2 = {0, 0}, c3 = {0, 0};

    #pragma unroll
    for (int pt = 0; pt < 3; ++pt) {
        int idx = pt * 8 + (h ^ (pt & 7));
        uint4 ad = s_ad[wv2][idx];
        uint4 wd = s_wt[wv2][idx];
        w0[pt] = __builtin_bit_cast(f16x2, wd.x);
        w1_[pt] = __builtin_bit_cast(f16x2, wd.y);
        w2_[pt] = __builtin_bit_cast(f16x2, wd.z);
        w3[pt] = __builtin_bit_cast(f16x2, wd.w);
        v00[pt] = __builtin_bit_cast(f16x2, *(const unsigned int*)(vb + ad.x));
        v10[pt] = __builtin_bit_cast(f16x2, *(const unsigned int*)(vb + ad.y));
        v01[pt] = __builtin_bit_cast(f16x2, *(const unsigned int*)(vb + ad.z));
        v11[pt] = __builtin_bit_cast(f16x2, *(const unsigned int*)(vb + ad.w));
    }
    #pragma unroll
    for (int pt = 0; pt < 16; ++pt) {
        int s = pt % 3;
        c0 += w0[s] * v00[s];
        c1 += w1_[s] * v10[s];
        c2 += w2_[s] * v01[s];
        c3 += w3[s] * v11[s];
        if (pt + 3 < 16) {
            int np = pt + 3;
            int idx = np * 8 + (h ^ (np & 7));
            uint4 ad = s_ad[wv2][idx];
            uint4 wd = s_wt[wv2][idx];
            w0[s] = __builtin_bit_cast(f16x2, wd.x);
            w1_[s] = __builtin_bit_cast(f16x2, wd.y);
            w2_[s] = __builtin_bit_cast(f16x2, wd.z);
            w3[s] = __builtin_bit_cast(f16x2, wd.w);
            v00[s] = __builtin_bit_cast(f16x2, *(const unsigned int*)(vb + ad.x));
            v10[s] = __builtin_bit_cast(f16x2, *(const unsigned int*)(vb + ad.y));
            v01[s] = __builtin_bit_cast(f16x2, *(const unsigned int*)(vb + ad.z));
            v11[s] = __builtin_bit_cast(f16x2, *(const unsigned int*)(vb + ad.w));
        }
    }
    float a0 = ((float)c0[0] + (float)c1[0]) + ((float)c2[0] + (float)c3[0]);
    float a1 = ((float)c0[1] + (float)c1[1]) + ((float)c2[1] + (float)c3[1]);
    u16 o[2] = { f2bf(a0), f2bf(a1) };
    *(ushort2*)(out + (size_t)n * 256 + h * 32 + dq * 2) = *(ushort2*)o;
}

extern "C" void kernel_launch(void* const* d_in, const int* in_sizes, int n_in,
                              void* d_out, int out_size, void* d_ws, size_t ws_size,
                              hipStream_t stream) {
    const float* src    = (const float*)d_in[0];
    const float* pos    = (const float*)d_in[1];
    const float* refp   = (const float*)d_in[2];
    const float* w_value= (const float*)d_in[3];
    const float* b_value= (const float*)d_in[4];
    const float* w_off  = (const float*)d_in[5];
    const float* b_off  = (const float*)d_in[6];
    const float* w_attn = (const float*)d_in[7];
    const float* b_attn = (const float*)d_in[8];
    const float* w_out  = (const float*)d_in[9];
    const float* b_out  = (const float*)d_in[10];
    const float* ln1_g  = (const float*)d_in[11];
    const float* ln1_b  = (const float*)d_in[12];
    const float* w1     = (const float*)d_in[13];
    const float* b1     = (const float*)d_in[14];
    const float* w2     = (const float*)d_in[15];
    const float* b2     = (const float*)d_in[16];
    const float* ln2_g  = (const float*)d_in[17];
    const float* ln2_b  = (const float*)d_in[18];

    // ws layout (bytes), liveness-packed:
    //   srcb [0, 11523072)         bf16; dead after gemm5; then Sb
    //   Vh   [11523072, 23046144)  fp16 value; dead after sample
    //   qb   [23046144, 34569216)  bf16; dead after gemm5
    //   X    [11523072, 34569216)  f32  LN1 out (overlay)
    //   OA   [34569216, 69138432)  f32; dead after sample
    //   Xb   [34569216, 46092288)  bf16 LN1 out (overlay)
    //   Hb   [46092288, 92184576)  bf16 FFN hidden
    //   weights [92184576, ...)
    char* w = (char*)d_ws;
    u16*   srcb = (u16*)w;
    u16*   Sb   = srcb;
    u16*   Vh   = (u16*)(w + 11523072);
    u16*   qb   = (u16*)(w + 23046144);
    float* X    = (float*)(w + 11523072);
    float* OA   = (float*)(w + 34569216);
    u16*   Xb   = (u16*)(w + 34569216);
    u16*   Hb   = (u16*)(w + 46092288);
    char*  WB   = w + 92184576;
    u16* wv_t   = (u16*)WB;
    u16* woa_t  = wv_t + 65536;
    u16* wout_t = woa_t + 98304;
    u16* w1_t   = wout_t + 65536;
    u16* w2_t   = w1_t + 262144;
    float* boa  = (float*)(w2_t + 262144);
    float* out  = (float*)d_out;

    dim3 b256(256);
    int MB = (N_TOK + 127) / 128;   // 176

    wprep<<<dim3(8572), b256, 0, stream>>>(w_value, w_off, w_attn, w_out, w1, w2,
                                           b_off, b_attn, src, pos,
                                           wv_t, woa_t, wout_t, w1_t, w2_t, boa, srcb, qb);
    gemm5<<<dim3(5 * MB), b256, 0, stream>>>(srcb, qb, wv_t, woa_t, b_value, boa, Vh, OA);
    ms_sample<<<dim3(N_TOK / 2), b256, 0, stream>>>(Vh, OA, refp, Sb);
    gemm_ln<<<dim3((N_TOK + 63) / 64), b256, 0, stream>>>(Sb, wout_t, b_out, src,
                                                          ln1_g, ln1_b, X, Xb, N_TOK, 256);
    gemm2<<<dim3(8, MB), b256, 0, stream>>>(Xb, w1_t, b1, nullptr, Hb, N_TOK, 1024, 256, 1);
    gemm_ln<<<dim3((N_TOK + 63) / 64), b256, 0, stream>>>(Hb, w2_t, b2, X,
                                                          ln2_g, ln2_b, out, nullptr, N_TOK, 1024);
}

// Round 18
// 197.819 us; speedup vs baseline: 1.0467x; 1.0467x over previous
//
#include <hip/hip_runtime.h>
#include <hip/hip_bf16.h>
#include <math.h>

#define N_TOK 22506
#define LEN   11253

typedef unsigned short u16;
typedef __attribute__((ext_vector_type(8))) short short8;
typedef __attribute__((ext_vector_type(4))) float f32x4;
typedef _Float16 f16x2 __attribute__((ext_vector_type(2)));

#define GLOAD16(g, l) __builtin_amdgcn_global_load_lds( \
    (const __attribute__((address_space(1))) void*)(g), \
    (__attribute__((address_space(3))) void*)(l), 16, 0, 0)

static __device__ __forceinline__ u16 f2bf(float f) {
    unsigned int u = __builtin_bit_cast(unsigned int, f);
    u = (u + 0x7fffu + ((u >> 16) & 1u)) >> 16;
    return (u16)u;
}

// bijective XCD-chunked swizzle (m204)
static __device__ __forceinline__ int xcd_swz(int id, int nwg) {
    int q = nwg >> 3, r = nwg & 7;
    int xcd = id & 7, rank = id >> 3;
    return (xcd < r ? xcd * (q + 1) : r * (q + 1) + (xcd - r) * q) + rank;
}

// ---- weight transposes + bias concat + src/q bf16 conversion, one dispatch ----
__global__ __launch_bounds__(256) void wprep(
    const float* __restrict__ w_value, const float* __restrict__ w_off,
    const float* __restrict__ w_attn, const float* __restrict__ w_out,
    const float* __restrict__ w1, const float* __restrict__ w2,
    const float* __restrict__ b_off, const float* __restrict__ b_attn,
    const float* __restrict__ src, const float* __restrict__ pos,
    u16* __restrict__ wv_t, u16* __restrict__ woa_t, u16* __restrict__ wout_t,
    u16* __restrict__ w1_t, u16* __restrict__ w2_t, float* __restrict__ boa,
    u16* __restrict__ srcb, u16* __restrict__ qb)
{
    int i = blockIdx.x * 256 + threadIdx.x;
    if (i < 65536) {
        wv_t[(i & 255) * 256 + (i >> 8)] = f2bf(w_value[i]);
    } else if (i < 131072) {
        int j = i - 65536;
        woa_t[(j & 255) * 256 + (j >> 8)] = f2bf(w_off[j]);
    } else if (i < 163840) {
        int j = i - 131072;
        woa_t[65536 + (j & 127) * 256 + (j >> 7)] = f2bf(w_attn[j]);
    } else if (i < 229376) {
        int j = i - 163840;
        wout_t[(j & 255) * 256 + (j >> 8)] = f2bf(w_out[j]);
    } else if (i < 491520) {
        int j = i - 229376;
        w1_t[(j & 1023) * 256 + (j >> 10)] = f2bf(w1[j]);
    } else if (i < 753664) {
        int j = i - 491520;
        w2_t[(j & 255) * 1024 + (j >> 8)] = f2bf(w2[j]);
    } else if (i < 754048) {
        int j = i - 753664;
        boa[j] = (j < 256) ? b_off[j] : b_attn[j - 256];
    } else if (i < 754048 + 1440384) {
        int j = i - 754048;                 // float4 index over N_TOK*256
        float4 s = ((const float4*)src)[j];
        float4 p = ((const float4*)pos)[j];
        u16 sb[4] = { f2bf(s.x), f2bf(s.y), f2bf(s.z), f2bf(s.w) };
        u16 q4[4] = { f2bf(s.x + p.x), f2bf(s.y + p.y), f2bf(s.z + p.z), f2bf(s.w + p.w) };
        *(ushort4*)(srcb + (size_t)j * 4) = *(ushort4*)sb;
        *(ushort4*)(qb + (size_t)j * 4) = *(ushort4*)q4;
    }
}

// ============ fused value + off/attn GEMM: 128x128 tile, BK=32, 2-deep ============
// sid%5: p<2 -> value job (out Vh fp16); else off|attn job (out OA f32).
__global__ __launch_bounds__(256) void gemm5(
    const u16* __restrict__ srcb, const u16* __restrict__ qb,
    const u16* __restrict__ wv_t, const u16* __restrict__ woa_t,
    const float* __restrict__ b_value, const float* __restrict__ boa,
    u16* __restrict__ Vh, float* __restrict__ OA)
{
    __shared__ u16 As[2 * 4096];
    __shared__ u16 Bs[2 * 4096];
    int tid = threadIdx.x;
    int lane = tid & 63, wid = tid >> 6;
    int wr = wid >> 1, wc = wid & 1;

    int sid = xcd_swz(blockIdx.x, gridDim.x);
    int p = sid % 5, bm = (sid / 5) * 128;
    int job = p < 2 ? 0 : 1;
    int bn = job ? (p - 2) * 128 : p * 128;
    const u16* A  = job ? qb : srcb;
    const u16* Bt = job ? woa_t : wv_t;

    f32x4 acc[4][4] = {};
    int srcslot = ((lane & 3) ^ ((lane >> 2) & 3) ^ ((lane >> 4) & 3)) << 3;
    int lrow = lane >> 2;

    auto stage = [&](int t) {
        int k0 = t * 32, sb = t & 1;
        #pragma unroll
        for (int c = 0; c < 2; ++c) {
            int rr = wid * 32 + c * 16 + lrow;
            int ra = bm + rr; ra = ra < N_TOK ? ra : N_TOK - 1;
            GLOAD16(A + (size_t)ra * 256 + k0 + srcslot,
                    (char*)As + sb * 8192 + wid * 2048 + c * 1024);
            GLOAD16(Bt + (size_t)(bn + rr) * 256 + k0 + srcslot,
                    (char*)Bs + sb * 8192 + wid * 2048 + c * 1024);
        }
    };

    stage(0); stage(1);

    int rlo = lane & 15, khalf = lane >> 4;
    int fsl = ((khalf ^ (rlo & 3) ^ ((rlo >> 2) & 3)) << 3);

    for (int t = 0; t < 8; ++t) {
        if (t + 1 < 8) asm volatile("s_waitcnt vmcnt(8)" ::: "memory");
        else           asm volatile("s_waitcnt vmcnt(0)" ::: "memory");
        __builtin_amdgcn_s_barrier();
        __builtin_amdgcn_sched_barrier(0);

        const u16* a_lds = As + (t & 1) * 4096;
        const u16* b_lds = Bs + (t & 1) * 4096;
        short8 af[4], bf_[4];
        #pragma unroll
        for (int mi = 0; mi < 4; ++mi)
            af[mi] = *(const short8*)(a_lds + (wr * 64 + mi * 16 + rlo) * 32 + fsl);
        #pragma unroll
        for (int ni = 0; ni < 4; ++ni)
            bf_[ni] = *(const short8*)(b_lds + (wc * 64 + ni * 16 + rlo) * 32 + fsl);

        __builtin_amdgcn_s_setprio(1);
        #pragma unroll
        for (int mi = 0; mi < 4; ++mi)
            #pragma unroll
            for (int ni = 0; ni < 4; ++ni)
                acc[mi][ni] = __builtin_amdgcn_mfma_f32_16x16x32_bf16(
                    af[mi], bf_[ni], acc[mi][ni], 0, 0, 0);
        __builtin_amdgcn_s_setprio(0);

        __builtin_amdgcn_sched_barrier(0);
        asm volatile("s_waitcnt lgkmcnt(0)" ::: "memory");
        __builtin_amdgcn_s_barrier();
        if (t + 2 < 8) stage(t + 2);
    }

    int col_l = lane & 15, rgrp = lane >> 4;
    #pragma unroll
    for (int mi = 0; mi < 4; ++mi) {
        #pragma unroll
        for (int j = 0; j < 4; ++j) {
            int row = bm + wr * 64 + mi * 16 + rgrp * 4 + j;
            if (row >= N_TOK) continue;
            #pragma unroll
            for (int ni = 0; ni < 4; ++ni) {
                int col = bn + wc * 64 + ni * 16 + col_l;
                if (job) {
                    OA[(size_t)row * 384 + col] = acc[mi][ni][j] + boa[col];
                } else {
                    _Float16 hv = (_Float16)(acc[mi][ni][j] + b_value[col]);
                    Vh[(size_t)row * 256 + col] = __builtin_bit_cast(u16, hv);
                }
            }
        }
    }
}

// ============ bf16 MFMA GEMM: 128x128 tile, BK=32, 2-deep (FFN1) ============
__global__ __launch_bounds__(256) void gemm2(
    const u16* __restrict__ A, const u16* __restrict__ Bt,
    const float* __restrict__ bias, float* __restrict__ Cf, u16* __restrict__ Cb,
    int M, int Nc, int K, int relu)
{
    __shared__ u16 As[2 * 4096];
    __shared__ u16 Bs[2 * 4096];
    int tid = threadIdx.x;
    int lane = tid & 63, wid = tid >> 6;
    int wr = wid >> 1, wc = wid & 1;

    int nwg = gridDim.x * gridDim.y;
    int sid = xcd_swz(blockIdx.y * gridDim.x + blockIdx.x, nwg);
    int bm = (sid / gridDim.x) * 128, bn = (sid % gridDim.x) * 128;

    f32x4 acc[4][4] = {};
    int srcslot = ((lane & 3) ^ ((lane >> 2) & 3) ^ ((lane >> 4) & 3)) << 3;
    int lrow = lane >> 2;

    auto stage = [&](int t) {
        int k0 = t * 32, sb = t & 1;
        #pragma unroll
        for (int c = 0; c < 2; ++c) {
            int rr = wid * 32 + c * 16 + lrow;
            int ra = bm + rr; ra = ra < M ? ra : M - 1;
            GLOAD16(A + (size_t)ra * K + k0 + srcslot,
                    (char*)As + sb * 8192 + wid * 2048 + c * 1024);
            GLOAD16(Bt + (size_t)(bn + rr) * K + k0 + srcslot,
                    (char*)Bs + sb * 8192 + wid * 2048 + c * 1024);
        }
    };

    int KT = K >> 5;
    stage(0); if (KT > 1) stage(1);

    int rlo = lane & 15, khalf = lane >> 4;
    int fsl = ((khalf ^ (rlo & 3) ^ ((rlo >> 2) & 3)) << 3);

    for (int t = 0; t < KT; ++t) {
        if (t + 1 < KT) asm volatile("s_waitcnt vmcnt(8)" ::: "memory");
        else            asm volatile("s_waitcnt vmcnt(0)" ::: "memory");
        __builtin_amdgcn_s_barrier();
        __builtin_amdgcn_sched_barrier(0);

        const u16* a_lds = As + (t & 1) * 4096;
        const u16* b_lds = Bs + (t & 1) * 4096;
        short8 af[4], bf_[4];
        #pragma unroll
        for (int mi = 0; mi < 4; ++mi)
            af[mi] = *(const short8*)(a_lds + (wr * 64 + mi * 16 + rlo) * 32 + fsl);
        #pragma unroll
        for (int ni = 0; ni < 4; ++ni)
            bf_[ni] = *(const short8*)(b_lds + (wc * 64 + ni * 16 + rlo) * 32 + fsl);

        __builtin_amdgcn_s_setprio(1);
        #pragma unroll
        for (int mi = 0; mi < 4; ++mi)
            #pragma unroll
            for (int ni = 0; ni < 4; ++ni)
                acc[mi][ni] = __builtin_amdgcn_mfma_f32_16x16x32_bf16(
                    af[mi], bf_[ni], acc[mi][ni], 0, 0, 0);
        __builtin_amdgcn_s_setprio(0);

        __builtin_amdgcn_sched_barrier(0);
        asm volatile("s_waitcnt lgkmcnt(0)" ::: "memory");
        __builtin_amdgcn_s_barrier();
        if (t + 2 < KT) stage(t + 2);
    }

    int col_l = lane & 15, rgrp = lane >> 4;
    #pragma unroll
    for (int mi = 0; mi < 4; ++mi) {
        #pragma unroll
        for (int j = 0; j < 4; ++j) {
            int row = bm + wr * 64 + mi * 16 + rgrp * 4 + j;
            if (row >= M) continue;
            #pragma unroll
            for (int ni = 0; ni < 4; ++ni) {
                int col = bn + wc * 64 + ni * 16 + col_l;
                float v = acc[mi][ni][j];
                if (bias) v += bias[col];
                if (relu) v = fmaxf(v, 0.f);
                if (Cf) Cf[(size_t)row * Nc + col] = v;
                if (Cb) Cb[(size_t)row * Nc + col] = f2bf(v);
            }
        }
    }
}

// ============ pipelined Nc=256 GEMM + residual + LayerNorm, BM=64, BK=32, 3-deep ============
__global__ __launch_bounds__(256) void gemm_ln(
    const u16* __restrict__ A, const u16* __restrict__ Bt,
    const float* __restrict__ bias, const float* __restrict__ res,
    const float* __restrict__ g, const float* __restrict__ beta,
    float* __restrict__ outf, u16* __restrict__ outb,
    int M, int K)
{
    __shared__ u16 As[3 * 2048];
    __shared__ u16 Bs[3 * 8192];
    int tid = threadIdx.x;
    int lane = tid & 63, wc = tid >> 6;
    int bm = blockIdx.x * 64;
    f32x4 acc[4][4] = {};
    int srcslot = ((lane & 3) ^ ((lane >> 2) & 3) ^ ((lane >> 4) & 3)) << 3;
    int lrow = lane >> 2;

    auto stage = [&](int t) {
        int k0 = t * 32, sb = t % 3;
        int ra = bm + wc * 16 + lrow; ra = ra < M ? ra : M - 1;
        GLOAD16(A + (size_t)ra * K + k0 + srcslot,
                (char*)As + sb * 4096 + wc * 1024);
        #pragma unroll
        for (int i = 0; i < 4; ++i) {
            int cc = i * 64 + wc * 16 + lrow;
            GLOAD16(Bt + (size_t)cc * K + k0 + srcslot,
                    (char*)Bs + sb * 16384 + i * 4096 + wc * 1024);
        }
    };

    int KT = K >> 5;
    stage(0); stage(1); stage(2);

    int rlo = lane & 15, khalf = lane >> 4;
    int fsl = ((khalf ^ (rlo & 3) ^ ((rlo >> 2) & 3)) << 3);

    for (int t = 0; t < KT; ++t) {
        if (t + 2 < KT)      asm volatile("s_waitcnt vmcnt(10)" ::: "memory");
        else if (t + 1 < KT) asm volatile("s_waitcnt vmcnt(5)" ::: "memory");
        else                 asm volatile("s_waitcnt vmcnt(0)" ::: "memory");
        __builtin_amdgcn_s_barrier();
        __builtin_amdgcn_sched_barrier(0);

        const u16* a_lds = As + (t % 3) * 2048;
        const u16* b_lds = Bs + (t % 3) * 8192;
        short8 af[4], bf_[4];
        #pragma unroll
        for (int mi = 0; mi < 4; ++mi)
            af[mi] = *(const short8*)(a_lds + (mi * 16 + rlo) * 32 + fsl);
        #pragma unroll
        for (int ni = 0; ni < 4; ++ni)
            bf_[ni] = *(const short8*)(b_lds + (wc * 64 + ni * 16 + rlo) * 32 + fsl);

        __builtin_amdgcn_s_setprio(1);
        #pragma unroll
        for (int mi = 0; mi < 4; ++mi)
            #pragma unroll
            for (int ni = 0; ni < 4; ++ni)
                acc[mi][ni] = __builtin_amdgcn_mfma_f32_16x16x32_bf16(
                    af[mi], bf_[ni], acc[mi][ni], 0, 0, 0);
        __builtin_amdgcn_s_setprio(0);

        __builtin_amdgcn_sched_barrier(0);
        asm volatile("s_waitcnt lgkmcnt(0)" ::: "memory");
        __builtin_amdgcn_s_barrier();
        if (t + 3 < KT) stage(t + 3);
    }
    __syncthreads();

    float* red = (float*)As;
    int col_l = lane & 15, rgrp = lane >> 4;
    int colc[4]; float bias_c[4], g_c[4], be_c[4];
    #pragma unroll
    for (int ni = 0; ni < 4; ++ni) {
        colc[ni] = wc * 64 + ni * 16 + col_l;
        bias_c[ni] = bias[colc[ni]];
        g_c[ni]  = g[colc[ni]];
        be_c[ni] = beta[colc[ni]];
    }
    #pragma unroll
    for (int mi = 0; mi < 4; ++mi) {
        #pragma unroll
        for (int j = 0; j < 4; ++j) {
            int rl = mi * 16 + rgrp * 4 + j;
            int row = bm + rl;
            float s = 0.f, s2 = 0.f;
            if (row < M) {
                #pragma unroll
                for (int ni = 0; ni < 4; ++ni) {
                    float v = acc[mi][ni][j] + bias_c[ni] + res[(size_t)row * 256 + colc[ni]];
                    acc[mi][ni][j] = v;
                    s += v; s2 += v * v;
                }
            }
            #pragma unroll
            for (int d = 1; d < 16; d <<= 1) { s += __shfl_xor(s, d); s2 += __shfl_xor(s2, d); }
            if (col_l == 0) { red[wc * 64 + rl] = s; red[256 + wc * 64 + rl] = s2; }
        }
    }
    __syncthreads();
    if (tid < 64) {
        float s  = red[tid] + red[64 + tid] + red[128 + tid] + red[192 + tid];
        float s2 = red[256 + tid] + red[320 + tid] + red[384 + tid] + red[448 + tid];
        float mean = s * (1.f / 256.f);
        float var = s2 * (1.f / 256.f) - mean * mean;
        red[512 + tid] = mean;
        red[576 + tid] = rsqrtf(var + 1e-5f);
    }
    __syncthreads();
    #pragma unroll
    for (int mi = 0; mi < 4; ++mi) {
        #pragma unroll
        for (int j = 0; j < 4; ++j) {
            int rl = mi * 16 + rgrp * 4 + j;
            int row = bm + rl;
            if (row >= M) continue;
            float mean = red[512 + rl], rs = red[576 + rl];
            #pragma unroll
            for (int ni = 0; ni < 4; ++ni) {
                float o = g_c[ni] * (acc[mi][ni][j] - mean) * rs + be_c[ni];
                outf[(size_t)row * 256 + colc[ni]] = o;
                if (outb) outb[(size_t)row * 256 + colc[ni]] = f2bf(o);
            }
        }
    }
}

// ---- deformable sampling: 2 waves/token, fp16 value, packed v_pk_fma_f16 ----
__global__ __launch_bounds__(256) void ms_sample(
    const u16* __restrict__ value, const float* __restrict__ oa,
    const float* __restrict__ refp, u16* __restrict__ out)
{
    const int starts[4] = {0, 8464, 10580, 11109};
    const int sizes[4]  = {92, 46, 23, 12};
    int t = threadIdx.x;
    int wid = t >> 6, lane = t & 63;
    int wv2 = wid >> 1;
    int wpar = wid & 1;
    int n = blockIdx.x * 2 + wv2;   // grid = N_TOK/2 exactly

    __shared__ uint4 s_ad[2][128];
    __shared__ uint4 s_wt[2][128];

    const float* oan = oa + (size_t)n * 384;
    unsigned int tokbase = (n >= LEN) ? (unsigned)LEN : 0u;
    {
        int q = wpar * 64 + lane;         // q = h*16 + pt
        int h = q >> 4, pt = q & 15, l = pt >> 2;
        float logit = oan[256 + q];
        float m = logit;
        #pragma unroll
        for (int d = 1; d < 16; d <<= 1) m = fmaxf(m, __shfl_xor(m, d));
        float e = __expf(logit - m);
        float ssum = e;
        #pragma unroll
        for (int d = 1; d < 16; d <<= 1) ssum += __shfl_xor(ssum, d);
        float aw = e / ssum;
        float2 off2 = *(const float2*)(oan + 2 * q);
        float2 ref2 = *(const float2*)(refp + (size_t)n * 8 + l * 2);
        int wl = sizes[l];
        float wf = (float)wl;
        float x = ref2.x * wf - 0.5f + off2.x;
        float y = ref2.y * wf - 0.5f + off2.y;
        float x0f = floorf(x), y0f = floorf(y);
        float fx = x - x0f, fy = y - y0f;
        int x0 = (int)x0f, y0 = (int)y0f;
        int x1 = x0 + 1, y1 = y0 + 1;
        float gx = 1.f - fx, gy = 1.f - fy;
        bool bx0 = (unsigned)x0 < (unsigned)wl, bx1 = (unsigned)x1 < (unsigned)wl;
        bool by0 = (unsigned)y0 < (unsigned)wl, by1 = (unsigned)y1 < (unsigned)wl;
        float w00 = (bx0 && by0) ? gx * gy * aw : 0.f;
        float w10 = (bx1 && by0) ? fx * gy * aw : 0.f;
        float w01 = (bx0 && by1) ? gx * fy * aw : 0.f;
        float w11 = (bx1 && by1) ? fx * fy * aw : 0.f;
        int x0c = min(max(x0, 0), wl - 1), x1c = min(max(x1, 0), wl - 1);
        int y0c = min(max(y0, 0), wl - 1), y1c = min(max(y1, 0), wl - 1);
        unsigned int base = (tokbase + (unsigned)starts[l]) * 512u + (unsigned)(h * 64);
        unsigned int r0 = base + (unsigned)(y0c * wl) * 512u;
        unsigned int r1 = base + (unsigned)(y1c * wl) * 512u;
        int idx = pt * 8 + (h ^ (pt & 7));
        s_ad[wv2][idx] = make_uint4(r0 + (unsigned)x0c * 512u, r0 + (unsigned)x1c * 512u,
                                    r1 + (unsigned)x0c * 512u, r1 + (unsigned)x1c * 512u);
        s_wt[wv2][idx] = make_uint4(
            __builtin_bit_cast(unsigned int, __builtin_amdgcn_cvt_pkrtz(w00, w00)),
            __builtin_bit_cast(unsigned int, __builtin_amdgcn_cvt_pkrtz(w10, w10)),
            __builtin_bit_cast(unsigned int, __builtin_amdgcn_cvt_pkrtz(w01, w01)),
            __builtin_bit_cast(unsigned int, __builtin_amdgcn_cvt_pkrtz(w11, w11)));
    }
    asm volatile("s_waitcnt lgkmcnt(0)" ::: "memory");

    int h = wpar * 4 + (lane >> 4);
    int dq = lane & 15;
    const char* vb = (const char*)value + dq * 4;

    f16x2 v00[3], v10[3], v01[3], v11[3];
    f16x2 w0[3], w1_[3], w2_[3], w3[3];
    f16x2 c0 = {0, 0}, c1 = {0, 0}, c2 = {0, 0}, c3 = {0, 0};

    #pragma unroll
    for (int pt = 0; pt < 3; ++pt) {
        int idx = pt * 8 + (h ^ (pt & 7));
        uint4 ad = s_ad[wv2][idx];
        uint4 wd = s_wt[wv2][idx];
        w0[pt] = __builtin_bit_cast(f16x2, wd.x);
        w1_[pt] = __builtin_bit_cast(f16x2, wd.y);
        w2_[pt] = __builtin_bit_cast(f16x2, wd.z);
        w3[pt] = __builtin_bit_cast(f16x2, wd.w);
        v00[pt] = __builtin_bit_cast(f16x2, *(const unsigned int*)(vb + ad.x));
        v10[pt] = __builtin_bit_cast(f16x2, *(const unsigned int*)(vb + ad.y));
        v01[pt] = __builtin_bit_cast(f16x2, *(const unsigned int*)(vb + ad.z));
        v11[pt] = __builtin_bit_cast(f16x2, *(const unsigned int*)(vb + ad.w));
    }
    #pragma unroll
    for (int pt = 0; pt < 16; ++pt) {
        int s = pt % 3;
        c0 += w0[s] * v00[s];
        c1 += w1_[s] * v10[s];
        c2 += w2_[s] * v01[s];
        c3 += w3[s] * v11[s];
        if (pt + 3 < 16) {
            int np = pt + 3;
            int idx = np * 8 + (h ^ (np & 7));
            uint4 ad = s_ad[wv2][idx];
            uint4 wd = s_wt[wv2][idx];
            w0[s] = __builtin_bit_cast(f16x2, wd.x);
            w1_[s] = __builtin_bit_cast(f16x2, wd.y);
            w2_[s] = __builtin_bit_cast(f16x2, wd.z);
            w3[s] = __builtin_bit_cast(f16x2, wd.w);
            v00[s] = __builtin_bit_cast(f16x2, *(const unsigned int*)(vb + ad.x));
            v10[s] = __builtin_bit_cast(f16x2, *(const unsigned int*)(vb + ad.y));
            v01[s] = __builtin_bit_cast(f16x2, *(const unsigned int*)(vb + ad.z));
            v11[s] = __builtin_bit_cast(f16x2, *(const unsigned int*)(vb + ad.w));
        }
    }
    float a0 = ((float)c0[0] + (float)c1[0]) + ((float)c2[0] + (float)c3[0]);
    float a1 = ((float)c0[1] + (float)c1[1]) + ((float)c2[1] + (float)c3[1]);
    u16 o[2] = { f2bf(a0), f2bf(a1) };
    *(ushort2*)(out + (size_t)n * 256 + h * 32 + dq * 2) = *(ushort2*)o;
}

extern "C" void kernel_launch(void* const* d_in, const int* in_sizes, int n_in,
                              void* d_out, int out_size, void* d_ws, size_t ws_size,
                              hipStream_t stream) {
    const float* src    = (const float*)d_in[0];
    const float* pos    = (const float*)d_in[1];
    const float* refp   = (const float*)d_in[2];
    const float* w_value= (const float*)d_in[3];
    const float* b_value= (const float*)d_in[4];
    const float* w_off  = (const float*)d_in[5];
    const float* b_off  = (const float*)d_in[6];
    const float* w_attn = (const float*)d_in[7];
    const float* b_attn = (const float*)d_in[8];
    const float* w_out  = (const float*)d_in[9];
    const float* b_out  = (const float*)d_in[10];
    const float* ln1_g  = (const float*)d_in[11];
    const float* ln1_b  = (const float*)d_in[12];
    const float* w1     = (const float*)d_in[13];
    const float* b1     = (const float*)d_in[14];
    const float* w2     = (const float*)d_in[15];
    const float* b2     = (const float*)d_in[16];
    const float* ln2_g  = (const float*)d_in[17];
    const float* ln2_b  = (const float*)d_in[18];

    // ws layout (bytes), liveness-packed:
    //   srcb [0, 11523072)         bf16; dead after gemm5; then Sb
    //   Vh   [11523072, 23046144)  fp16 value; dead after sample
    //   qb   [23046144, 34569216)  bf16; dead after gemm5
    //   X    [11523072, 34569216)  f32  LN1 out (overlay)
    //   OA   [34569216, 69138432)  f32; dead after sample
    //   Xb   [34569216, 46092288)  bf16 LN1 out (overlay)
    //   Hb   [46092288, 92184576)  bf16 FFN hidden
    //   weights [92184576, ...)
    char* w = (char*)d_ws;
    u16*   srcb = (u16*)w;
    u16*   Sb   = srcb;
    u16*   Vh   = (u16*)(w + 11523072);
    u16*   qb   = (u16*)(w + 23046144);
    float* X    = (float*)(w + 11523072);
    float* OA   = (float*)(w + 34569216);
    u16*   Xb   = (u16*)(w + 34569216);
    u16*   Hb   = (u16*)(w + 46092288);
    char*  WB   = w + 92184576;
    u16* wv_t   = (u16*)WB;
    u16* woa_t  = wv_t + 65536;
    u16* wout_t = woa_t + 98304;
    u16* w1_t   = wout_t + 65536;
    u16* w2_t   = w1_t + 262144;
    float* boa  = (float*)(w2_t + 262144);
    float* out  = (float*)d_out;

    dim3 b256(256);
    int MB = (N_TOK + 127) / 128;   // 176

    wprep<<<dim3(8572), b256, 0, stream>>>(w_value, w_off, w_attn, w_out, w1, w2,
                                           b_off, b_attn, src, pos,
                                           wv_t, woa_t, wout_t, w1_t, w2_t, boa, srcb, qb);
    gemm5<<<dim3(5 * MB), b256, 0, stream>>>(srcb, qb, wv_t, woa_t, b_value, boa, Vh, OA);
    ms_sample<<<dim3(N_TOK / 2), b256, 0, stream>>>(Vh, OA, refp, Sb);
    gemm_ln<<<dim3((N_TOK + 63) / 64), b256, 0, stream>>>(Sb, wout_t, b_out, src,
                                                          ln1_g, ln1_b, X, Xb, N_TOK, 256);
    gemm2<<<dim3(8, MB), b256, 0, stream>>>(Xb, w1_t, b1, nullptr, Hb, N_TOK, 1024, 256, 1);
    gemm_ln<<<dim3((N_TOK + 63) / 64), b256, 0, stream>>>(Hb, w2_t, b2, X,
                                                          ln2_g, ln2_b, out, nullptr, N_TOK, 1024);
}

// Round 19
// 189.423 us; speedup vs baseline: 1.0931x; 1.0443x over previous
//
#include <hip/hip_runtime.h>
#include <hip/hip_bf16.h>
#include <math.h>

#define N_TOK 22506
#define LEN   11253

typedef unsigned short u16;
typedef __attribute__((ext_vector_type(8))) short short8;
typedef __attribute__((ext_vector_type(4))) float f32x4;
typedef _Float16 f16x2 __attribute__((ext_vector_type(2)));

#define GLOAD16(g, l) __builtin_amdgcn_global_load_lds( \
    (const __attribute__((address_space(1))) void*)(g), \
    (__attribute__((address_space(3))) void*)(l), 16, 0, 0)

static __device__ __forceinline__ u16 f2bf(float f) {
    unsigned int u = __builtin_bit_cast(unsigned int, f);
    u = (u + 0x7fffu + ((u >> 16) & 1u)) >> 16;
    return (u16)u;
}

// bijective XCD-chunked swizzle (m204)
static __device__ __forceinline__ int xcd_swz(int id, int nwg) {
    int q = nwg >> 3, r = nwg & 7;
    int xcd = id & 7, rank = id >> 3;
    return (xcd < r ? xcd * (q + 1) : r * (q + 1) + (xcd - r) * q) + rank;
}

// ---- weight transposes + bias concat + src/q bf16 conversion, one dispatch ----
__global__ __launch_bounds__(256) void wprep(
    const float* __restrict__ w_value, const float* __restrict__ w_off,
    const float* __restrict__ w_attn, const float* __restrict__ w_out,
    const float* __restrict__ w1, const float* __restrict__ w2,
    const float* __restrict__ b_off, const float* __restrict__ b_attn,
    const float* __restrict__ src, const float* __restrict__ pos,
    u16* __restrict__ wv_t, u16* __restrict__ woa_t, u16* __restrict__ wout_t,
    u16* __restrict__ w1_t, u16* __restrict__ w2_t, float* __restrict__ boa,
    u16* __restrict__ srcb, u16* __restrict__ qb)
{
    int i = blockIdx.x * 256 + threadIdx.x;
    if (i < 65536) {
        wv_t[(i & 255) * 256 + (i >> 8)] = f2bf(w_value[i]);
    } else if (i < 131072) {
        int j = i - 65536;
        woa_t[(j & 255) * 256 + (j >> 8)] = f2bf(w_off[j]);
    } else if (i < 163840) {
        int j = i - 131072;
        woa_t[65536 + (j & 127) * 256 + (j >> 7)] = f2bf(w_attn[j]);
    } else if (i < 229376) {
        int j = i - 163840;
        wout_t[(j & 255) * 256 + (j >> 8)] = f2bf(w_out[j]);
    } else if (i < 491520) {
        int j = i - 229376;
        w1_t[(j & 1023) * 256 + (j >> 10)] = f2bf(w1[j]);
    } else if (i < 753664) {
        int j = i - 491520;
        w2_t[(j & 255) * 1024 + (j >> 8)] = f2bf(w2[j]);
    } else if (i < 754048) {
        int j = i - 753664;
        boa[j] = (j < 256) ? b_off[j] : b_attn[j - 256];
    } else if (i < 754048 + 1440384) {
        int j = i - 754048;                 // float4 index over N_TOK*256
        float4 s = ((const float4*)src)[j];
        float4 p = ((const float4*)pos)[j];
        u16 sb[4] = { f2bf(s.x), f2bf(s.y), f2bf(s.z), f2bf(s.w) };
        u16 q4[4] = { f2bf(s.x + p.x), f2bf(s.y + p.y), f2bf(s.z + p.z), f2bf(s.w + p.w) };
        *(ushort4*)(srcb + (size_t)j * 4) = *(ushort4*)sb;
        *(ushort4*)(qb + (size_t)j * 4) = *(ushort4*)q4;
    }
}

// ============ fused value + off/attn GEMM: 128x128 tile, BK=32, 2-deep ============
__global__ __launch_bounds__(256) void gemm5(
    const u16* __restrict__ srcb, const u16* __restrict__ qb,
    const u16* __restrict__ wv_t, const u16* __restrict__ woa_t,
    const float* __restrict__ b_value, const float* __restrict__ boa,
    u16* __restrict__ Vh, float* __restrict__ OA)
{
    __shared__ u16 As[2 * 4096];
    __shared__ u16 Bs[2 * 4096];
    int tid = threadIdx.x;
    int lane = tid & 63, wid = tid >> 6;
    int wr = wid >> 1, wc = wid & 1;

    int sid = xcd_swz(blockIdx.x, gridDim.x);
    int p = sid % 5, bm = (sid / 5) * 128;
    int job = p < 2 ? 0 : 1;
    int bn = job ? (p - 2) * 128 : p * 128;
    const u16* A  = job ? qb : srcb;
    const u16* Bt = job ? woa_t : wv_t;

    f32x4 acc[4][4] = {};
    int srcslot = ((lane & 3) ^ ((lane >> 2) & 3) ^ ((lane >> 4) & 3)) << 3;
    int lrow = lane >> 2;

    auto stage = [&](int t) {
        int k0 = t * 32, sb = t & 1;
        #pragma unroll
        for (int c = 0; c < 2; ++c) {
            int rr = wid * 32 + c * 16 + lrow;
            int ra = bm + rr; ra = ra < N_TOK ? ra : N_TOK - 1;
            GLOAD16(A + (size_t)ra * 256 + k0 + srcslot,
                    (char*)As + sb * 8192 + wid * 2048 + c * 1024);
            GLOAD16(Bt + (size_t)(bn + rr) * 256 + k0 + srcslot,
                    (char*)Bs + sb * 8192 + wid * 2048 + c * 1024);
        }
    };

    stage(0); stage(1);

    int rlo = lane & 15, khalf = lane >> 4;
    int fsl = ((khalf ^ (rlo & 3) ^ ((rlo >> 2) & 3)) << 3);

    for (int t = 0; t < 8; ++t) {
        if (t + 1 < 8) asm volatile("s_waitcnt vmcnt(4)" ::: "memory");
        else           asm volatile("s_waitcnt vmcnt(0)" ::: "memory");
        __builtin_amdgcn_s_barrier();
        __builtin_amdgcn_sched_barrier(0);

        const u16* a_lds = As + (t & 1) * 4096;
        const u16* b_lds = Bs + (t & 1) * 4096;
        short8 af[4], bf_[4];
        #pragma unroll
        for (int mi = 0; mi < 4; ++mi)
            af[mi] = *(const short8*)(a_lds + (wr * 64 + mi * 16 + rlo) * 32 + fsl);
        #pragma unroll
        for (int ni = 0; ni < 4; ++ni)
            bf_[ni] = *(const short8*)(b_lds + (wc * 64 + ni * 16 + rlo) * 32 + fsl);

        __builtin_amdgcn_s_setprio(1);
        #pragma unroll
        for (int mi = 0; mi < 4; ++mi)
            #pragma unroll
            for (int ni = 0; ni < 4; ++ni)
                acc[mi][ni] = __builtin_amdgcn_mfma_f32_16x16x32_bf16(
                    af[mi], bf_[ni], acc[mi][ni], 0, 0, 0);
        __builtin_amdgcn_s_setprio(0);

        __builtin_amdgcn_sched_barrier(0);
        asm volatile("s_waitcnt lgkmcnt(0)" ::: "memory");
        __builtin_amdgcn_s_barrier();
        if (t + 2 < 8) stage(t + 2);
    }

    int col_l = lane & 15, rgrp = lane >> 4;
    #pragma unroll
    for (int mi = 0; mi < 4; ++mi) {
        #pragma unroll
        for (int j = 0; j < 4; ++j) {
            int row = bm + wr * 64 + mi * 16 + rgrp * 4 + j;
            if (row >= N_TOK) continue;
            #pragma unroll
            for (int ni = 0; ni < 4; ++ni) {
                int col = bn + wc * 64 + ni * 16 + col_l;
                if (job) {
                    OA[(size_t)row * 384 + col] = acc[mi][ni][j] + boa[col];
                } else {
                    _Float16 hv = (_Float16)(acc[mi][ni][j] + b_value[col]);
                    Vh[(size_t)row * 256 + col] = __builtin_bit_cast(u16, hv);
                }
            }
        }
    }
}

// ====== split-K bf16 MFMA GEMM (FFN1): 128x128 tile, K=256 split 2x128, BK=32 ======
// 512 thr = 8 waves; group g = wid>>2 computes K[g*128, g*128+128), then LDS reduce.
__global__ __launch_bounds__(512) void gemm2(
    const u16* __restrict__ A, const u16* __restrict__ Bt,
    const float* __restrict__ bias, u16* __restrict__ Cb,
    int M, int Nc, int K, int relu)
{
    __shared__ char smem[65536];   // [grp][buf] A 8KB, then B at +32KB; reduce reuses all
    int tid = threadIdx.x;
    int lane = tid & 63, wid = tid >> 6;
    int grp = wid >> 2, wg = wid & 3;
    int wr = wg >> 1, wc = wg & 1;

    int nwg = gridDim.x * gridDim.y;
    int sid = xcd_swz(blockIdx.y * gridDim.x + blockIdx.x, nwg);
    int bm = (sid / gridDim.x) * 128, bn = (sid % gridDim.x) * 128;

    f32x4 acc[4][4] = {};
    int srcslot = ((lane & 3) ^ ((lane >> 2) & 3) ^ ((lane >> 4) & 3)) << 3;
    int lrow = lane >> 2;
    int kbase = grp * (K >> 1);
    int KTg = (K >> 1) >> 5;   // 4 for K=256

    char* Abase = smem + grp * 16384;
    char* Bbase = smem + 32768 + grp * 16384;

    auto stage = [&](int t) {
        int k0 = kbase + t * 32, sb = t & 1;
        #pragma unroll
        for (int c = 0; c < 2; ++c) {
            int rr = wg * 32 + c * 16 + lrow;
            int ra = bm + rr; ra = ra < M ? ra : M - 1;
            GLOAD16(A + (size_t)ra * K + k0 + srcslot,
                    Abase + sb * 8192 + wg * 2048 + c * 1024);
            GLOAD16(Bt + (size_t)(bn + rr) * K + k0 + srcslot,
                    Bbase + sb * 8192 + wg * 2048 + c * 1024);
        }
    };

    stage(0); stage(1);

    int rlo = lane & 15, khalf = lane >> 4;
    int fsl = ((khalf ^ (rlo & 3) ^ ((rlo >> 2) & 3)) << 3);

    for (int t = 0; t < KTg; ++t) {
        if (t + 1 < KTg) asm volatile("s_waitcnt vmcnt(4)" ::: "memory");
        else             asm volatile("s_waitcnt vmcnt(0)" ::: "memory");
        __builtin_amdgcn_s_barrier();
        __builtin_amdgcn_sched_barrier(0);

        const u16* a_lds = (const u16*)(Abase + (t & 1) * 8192);
        const u16* b_lds = (const u16*)(Bbase + (t & 1) * 8192);
        short8 af[4], bf_[4];
        #pragma unroll
        for (int mi = 0; mi < 4; ++mi)
            af[mi] = *(const short8*)(a_lds + (wr * 64 + mi * 16 + rlo) * 32 + fsl);
        #pragma unroll
        for (int ni = 0; ni < 4; ++ni)
            bf_[ni] = *(const short8*)(b_lds + (wc * 64 + ni * 16 + rlo) * 32 + fsl);

        __builtin_amdgcn_s_setprio(1);
        #pragma unroll
        for (int mi = 0; mi < 4; ++mi)
            #pragma unroll
            for (int ni = 0; ni < 4; ++ni)
                acc[mi][ni] = __builtin_amdgcn_mfma_f32_16x16x32_bf16(
                    af[mi], bf_[ni], acc[mi][ni], 0, 0, 0);
        __builtin_amdgcn_s_setprio(0);

        __builtin_amdgcn_sched_barrier(0);
        asm volatile("s_waitcnt lgkmcnt(0)" ::: "memory");
        __builtin_amdgcn_s_barrier();
        if (t + 2 < KTg) stage(t + 2);
    }

    // cross-group reduction: red[q*256 + tid0], q = (mi*4+ni)*4+j (conflict-free)
    __syncthreads();
    float* red = (float*)smem;
    if (grp == 1) {
        int t0 = tid - 256;
        #pragma unroll
        for (int mi = 0; mi < 4; ++mi)
            #pragma unroll
            for (int ni = 0; ni < 4; ++ni)
                #pragma unroll
                for (int j = 0; j < 4; ++j)
                    red[((mi * 4 + ni) * 4 + j) * 256 + t0] = acc[mi][ni][j];
    }
    __syncthreads();
    if (grp == 0) {
        #pragma unroll
        for (int mi = 0; mi < 4; ++mi)
            #pragma unroll
            for (int ni = 0; ni < 4; ++ni)
                #pragma unroll
                for (int j = 0; j < 4; ++j)
                    acc[mi][ni][j] += red[((mi * 4 + ni) * 4 + j) * 256 + tid];

        int col_l = lane & 15, rgrp = lane >> 4;
        #pragma unroll
        for (int mi = 0; mi < 4; ++mi) {
            #pragma unroll
            for (int j = 0; j < 4; ++j) {
                int row = bm + wr * 64 + mi * 16 + rgrp * 4 + j;
                if (row >= M) continue;
                #pragma unroll
                for (int ni = 0; ni < 4; ++ni) {
                    int col = bn + wc * 64 + ni * 16 + col_l;
                    float v = acc[mi][ni][j] + bias[col];
                    if (relu) v = fmaxf(v, 0.f);
                    Cb[(size_t)row * Nc + col] = f2bf(v);
                }
            }
        }
    }
}

// ============ pipelined Nc=256 GEMM + residual + LayerNorm, BM=64, BK=32, 3-deep ============
__global__ __launch_bounds__(256) void gemm_ln(
    const u16* __restrict__ A, const u16* __restrict__ Bt,
    const float* __restrict__ bias, const float* __restrict__ res,
    const float* __restrict__ g, const float* __restrict__ beta,
    float* __restrict__ outf, u16* __restrict__ outb,
    int M, int K)
{
    __shared__ u16 As[3 * 2048];
    __shared__ u16 Bs[3 * 8192];
    int tid = threadIdx.x;
    int lane = tid & 63, wc = tid >> 6;
    int bm = blockIdx.x * 64;
    f32x4 acc[4][4] = {};
    int srcslot = ((lane & 3) ^ ((lane >> 2) & 3) ^ ((lane >> 4) & 3)) << 3;
    int lrow = lane >> 2;

    auto stage = [&](int t) {
        int k0 = t * 32, sb = t % 3;
        int ra = bm + wc * 16 + lrow; ra = ra < M ? ra : M - 1;
        GLOAD16(A + (size_t)ra * K + k0 + srcslot,
                (char*)As + sb * 4096 + wc * 1024);
        #pragma unroll
        for (int i = 0; i < 4; ++i) {
            int cc = i * 64 + wc * 16 + lrow;
            GLOAD16(Bt + (size_t)cc * K + k0 + srcslot,
                    (char*)Bs + sb * 16384 + i * 4096 + wc * 1024);
        }
    };

    int KT = K >> 5;
    stage(0); stage(1); stage(2);

    int rlo = lane & 15, khalf = lane >> 4;
    int fsl = ((khalf ^ (rlo & 3) ^ ((rlo >> 2) & 3)) << 3);

    for (int t = 0; t < KT; ++t) {
        if (t + 2 < KT)      asm volatile("s_waitcnt vmcnt(10)" ::: "memory");
        else if (t + 1 < KT) asm volatile("s_waitcnt vmcnt(5)" ::: "memory");
        else                 asm volatile("s_waitcnt vmcnt(0)" ::: "memory");
        __builtin_amdgcn_s_barrier();
        __builtin_amdgcn_sched_barrier(0);

        const u16* a_lds = As + (t % 3) * 2048;
        const u16* b_lds = Bs + (t % 3) * 8192;
        short8 af[4], bf_[4];
        #pragma unroll
        for (int mi = 0; mi < 4; ++mi)
            af[mi] = *(const short8*)(a_lds + (mi * 16 + rlo) * 32 + fsl);
        #pragma unroll
        for (int ni = 0; ni < 4; ++ni)
            bf_[ni] = *(const short8*)(b_lds + (wc * 64 + ni * 16 + rlo) * 32 + fsl);

        __builtin_amdgcn_s_setprio(1);
        #pragma unroll
        for (int mi = 0; mi < 4; ++mi)
            #pragma unroll
            for (int ni = 0; ni < 4; ++ni)
                acc[mi][ni] = __builtin_amdgcn_mfma_f32_16x16x32_bf16(
                    af[mi], bf_[ni], acc[mi][ni], 0, 0, 0);
        __builtin_amdgcn_s_setprio(0);

        __builtin_amdgcn_sched_barrier(0);
        asm volatile("s_waitcnt lgkmcnt(0)" ::: "memory");
        __builtin_amdgcn_s_barrier();
        if (t + 3 < KT) stage(t + 3);
    }
    __syncthreads();

    float* red = (float*)As;
    int col_l = lane & 15, rgrp = lane >> 4;
    int colc[4]; float bias_c[4], g_c[4], be_c[4];
    #pragma unroll
    for (int ni = 0; ni < 4; ++ni) {
        colc[ni] = wc * 64 + ni * 16 + col_l;
        bias_c[ni] = bias[colc[ni]];
        g_c[ni]  = g[colc[ni]];
        be_c[ni] = beta[colc[ni]];
    }
    #pragma unroll
    for (int mi = 0; mi < 4; ++mi) {
        #pragma unroll
        for (int j = 0; j < 4; ++j) {
            int rl = mi * 16 + rgrp * 4 + j;
            int row = bm + rl;
            float s = 0.f, s2 = 0.f;
            if (row < M) {
                #pragma unroll
                for (int ni = 0; ni < 4; ++ni) {
                    float v = acc[mi][ni][j] + bias_c[ni] + res[(size_t)row * 256 + colc[ni]];
                    acc[mi][ni][j] = v;
                    s += v; s2 += v * v;
                }
            }
            #pragma unroll
            for (int d = 1; d < 16; d <<= 1) { s += __shfl_xor(s, d); s2 += __shfl_xor(s2, d); }
            if (col_l == 0) { red[wc * 64 + rl] = s; red[256 + wc * 64 + rl] = s2; }
        }
    }
    __syncthreads();
    if (tid < 64) {
        float s  = red[tid] + red[64 + tid] + red[128 + tid] + red[192 + tid];
        float s2 = red[256 + tid] + red[320 + tid] + red[384 + tid] + red[448 + tid];
        float mean = s * (1.f / 256.f);
        float var = s2 * (1.f / 256.f) - mean * mean;
        red[512 + tid] = mean;
        red[576 + tid] = rsqrtf(var + 1e-5f);
    }
    __syncthreads();
    #pragma unroll
    for (int mi = 0; mi < 4; ++mi) {
        #pragma unroll
        for (int j = 0; j < 4; ++j) {
            int rl = mi * 16 + rgrp * 4 + j;
            int row = bm + rl;
            if (row >= M) continue;
            float mean = red[512 + rl], rs = red[576 + rl];
            #pragma unroll
            for (int ni = 0; ni < 4; ++ni) {
                float o = g_c[ni] * (acc[mi][ni][j] - mean) * rs + be_c[ni];
                outf[(size_t)row * 256 + colc[ni]] = o;
                if (outb) outb[(size_t)row * 256 + colc[ni]] = f2bf(o);
            }
        }
    }
}

// ---- deformable sampling: 2 waves/token, fp16 value, packed v_pk_fma_f16 ----
__global__ __launch_bounds__(256) void ms_sample(
    const u16* __restrict__ value, const float* __restrict__ oa,
    const float* __restrict__ refp, u16* __restrict__ out)
{
    const int starts[4] = {0, 8464, 10580, 11109};
    const int sizes[4]  = {92, 46, 23, 12};
    int t = threadIdx.x;
    int wid = t >> 6, lane = t & 63;
    int wv2 = wid >> 1;
    int wpar = wid & 1;
    int n = blockIdx.x * 2 + wv2;   // grid = N_TOK/2 exactly

    __shared__ uint4 s_ad[2][128];
    __shared__ uint4 s_wt[2][128];

    const float* oan = oa + (size_t)n * 384;
    unsigned int tokbase = (n >= LEN) ? (unsigned)LEN : 0u;
    {
        int q = wpar * 64 + lane;         // q = h*16 + pt
        int h = q >> 4, pt = q & 15, l = pt >> 2;
        float logit = oan[256 + q];
        float m = logit;
        #pragma unroll
        for (int d = 1; d < 16; d <<= 1) m = fmaxf(m, __shfl_xor(m, d));
        float e = __expf(logit - m);
        float ssum = e;
        #pragma unroll
        for (int d = 1; d < 16; d <<= 1) ssum += __shfl_xor(ssum, d);
        float aw = e / ssum;
        float2 off2 = *(const float2*)(oan + 2 * q);
        float2 ref2 = *(const float2*)(refp + (size_t)n * 8 + l * 2);
        int wl = sizes[l];
        float wf = (float)wl;
        float x = ref2.x * wf - 0.5f + off2.x;
        float y = ref2.y * wf - 0.5f + off2.y;
        float x0f = floorf(x), y0f = floorf(y);
        float fx = x - x0f, fy = y - y0f;
        int x0 = (int)x0f, y0 = (int)y0f;
        int x1 = x0 + 1, y1 = y0 + 1;
        float gx = 1.f - fx, gy = 1.f - fy;
        bool bx0 = (unsigned)x0 < (unsigned)wl, bx1 = (unsigned)x1 < (unsigned)wl;
        bool by0 = (unsigned)y0 < (unsigned)wl, by1 = (unsigned)y1 < (unsigned)wl;
        float w00 = (bx0 && by0) ? gx * gy * aw : 0.f;
        float w10 = (bx1 && by0) ? fx * gy * aw : 0.f;
        float w01 = (bx0 && by1) ? gx * fy * aw : 0.f;
        float w11 = (bx1 && by1) ? fx * fy * aw : 0.f;
        int x0c = min(max(x0, 0), wl - 1), x1c = min(max(x1, 0), wl - 1);
        int y0c = min(max(y0, 0), wl - 1), y1c = min(max(y1, 0), wl - 1);
        unsigned int base = (tokbase + (unsigned)starts[l]) * 512u + (unsigned)(h * 64);
        unsigned int r0 = base + (unsigned)(y0c * wl) * 512u;
        unsigned int r1 = base + (unsigned)(y1c * wl) * 512u;
        int idx = pt * 8 + (h ^ (pt & 7));
        s_ad[wv2][idx] = make_uint4(r0 + (unsigned)x0c * 512u, r0 + (unsigned)x1c * 512u,
                                    r1 + (unsigned)x0c * 512u, r1 + (unsigned)x1c * 512u);
        s_wt[wv2][idx] = make_uint4(
            __builtin_bit_cast(unsigned int, __builtin_amdgcn_cvt_pkrtz(w00, w00)),
            __builtin_bit_cast(unsigned int, __builtin_amdgcn_cvt_pkrtz(w10, w10)),
            __builtin_bit_cast(unsigned int, __builtin_amdgcn_cvt_pkrtz(w01, w01)),
            __builtin_bit_cast(unsigned int, __builtin_amdgcn_cvt_pkrtz(w11, w11)));
    }
    asm volatile("s_waitcnt lgkmcnt(0)" ::: "memory");

    int h = wpar * 4 + (lane >> 4);
    int dq = lane & 15;
    const char* vb = (const char*)value + dq * 4;

    f16x2 v00[3], v10[3], v01[3], v11[3];
    f16x2 w0[3], w1_[3], w2_[3], w3[3];
    f16x2 c0 = {0, 0}, c1 = {0, 0}, c2 = {0, 0}, c3 = {0, 0};

    #pragma unroll
    for (int pt = 0; pt < 3; ++pt) {
        int idx = pt * 8 + (h ^ (pt & 7));
        uint4 ad = s_ad[wv2][idx];
        uint4 wd = s_wt[wv2][idx];
        w0[pt] = __builtin_bit_cast(f16x2, wd.x);
        w1_[pt] = __builtin_bit_cast(f16x2, wd.y);
        w2_[pt] = __builtin_bit_cast(f16x2, wd.z);
        w3[pt] = __builtin_bit_cast(f16x2, wd.w);
        v00[pt] = __builtin_bit_cast(f16x2, *(const unsigned int*)(vb + ad.x));
        v10[pt] = __builtin_bit_cast(f16x2, *(const unsigned int*)(vb + ad.y));
        v01[pt] = __builtin_bit_cast(f16x2, *(const unsigned int*)(vb + ad.z));
        v11[pt] = __builtin_bit_cast(f16x2, *(const unsigned int*)(vb + ad.w));
    }
    #pragma unroll
    for (int pt = 0; pt < 16; ++pt) {
        int s = pt % 3;
        c0 += w0[s] * v00[s];
        c1 += w1_[s] * v10[s];
        c2 += w2_[s] * v01[s];
        c3 += w3[s] * v11[s];
        if (pt + 3 < 16) {
            int np = pt + 3;
            int idx = np * 8 + (h ^ (np & 7));
            uint4 ad = s_ad[wv2][idx];
            uint4 wd = s_wt[wv2][idx];
            w0[s] = __builtin_bit_cast(f16x2, wd.x);
            w1_[s] = __builtin_bit_cast(f16x2, wd.y);
            w2_[s] = __builtin_bit_cast(f16x2, wd.z);
            w3[s] = __builtin_bit_cast(f16x2, wd.w);
            v00[s] = __builtin_bit_cast(f16x2, *(const unsigned int*)(vb + ad.x));
            v10[s] = __builtin_bit_cast(f16x2, *(const unsigned int*)(vb + ad.y));
            v01[s] = __builtin_bit_cast(f16x2, *(const unsigned int*)(vb + ad.z));
            v11[s] = __builtin_bit_cast(f16x2, *(const unsigned int*)(vb + ad.w));
        }
    }
    float a0 = ((float)c0[0] + (float)c1[0]) + ((float)c2[0] + (float)c3[0]);
    float a1 = ((float)c0[1] + (float)c1[1]) + ((float)c2[1] + (float)c3[1]);
    u16 o[2] = { f2bf(a0), f2bf(a1) };
    *(ushort2*)(out + (size_t)n * 256 + h * 32 + dq * 2) = *(ushort2*)o;
}

extern "C" void kernel_launch(void* const* d_in, const int* in_sizes, int n_in,
                              void* d_out, int out_size, void* d_ws, size_t ws_size,
                              hipStream_t stream) {
    const float* src    = (const float*)d_in[0];
    const float* pos    = (const float*)d_in[1];
    const float* refp   = (const float*)d_in[2];
    const float* w_value= (const float*)d_in[3];
    const float* b_value= (const float*)d_in[4];
    const float* w_off  = (const float*)d_in[5];
    const float* b_off  = (const float*)d_in[6];
    const float* w_attn = (const float*)d_in[7];
    const float* b_attn = (const float*)d_in[8];
    const float* w_out  = (const float*)d_in[9];
    const float* b_out  = (const float*)d_in[10];
    const float* ln1_g  = (const float*)d_in[11];
    const float* ln1_b  = (const float*)d_in[12];
    const float* w1     = (const float*)d_in[13];
    const float* b1     = (const float*)d_in[14];
    const float* w2     = (const float*)d_in[15];
    const float* b2     = (const float*)d_in[16];
    const float* ln2_g  = (const float*)d_in[17];
    const float* ln2_b  = (const float*)d_in[18];

    // ws layout (bytes), liveness-packed:
    //   srcb [0, 11523072)         bf16; dead after gemm5; then Sb
    //   Vh   [11523072, 23046144)  fp16 value; dead after sample
    //   qb   [23046144, 34569216)  bf16; dead after gemm5
    //   X    [11523072, 34569216)  f32  LN1 out (overlay)
    //   OA   [34569216, 69138432)  f32; dead after sample
    //   Xb   [34569216, 46092288)  bf16 LN1 out (overlay)
    //   Hb   [46092288, 92184576)  bf16 FFN hidden
    //   weights [92184576, ...)
    char* w = (char*)d_ws;
    u16*   srcb = (u16*)w;
    u16*   Sb   = srcb;
    u16*   Vh   = (u16*)(w + 11523072);
    u16*   qb   = (u16*)(w + 23046144);
    float* X    = (float*)(w + 11523072);
    float* OA   = (float*)(w + 34569216);
    u16*   Xb   = (u16*)(w + 34569216);
    u16*   Hb   = (u16*)(w + 46092288);
    char*  WB   = w + 92184576;
    u16* wv_t   = (u16*)WB;
    u16* woa_t  = wv_t + 65536;
    u16* wout_t = woa_t + 98304;
    u16* w1_t   = wout_t + 65536;
    u16* w2_t   = w1_t + 262144;
    float* boa  = (float*)(w2_t + 262144);
    float* out  = (float*)d_out;

    dim3 b256(256), b512(512);
    int MB = (N_TOK + 127) / 128;   // 176

    wprep<<<dim3(8572), b256, 0, stream>>>(w_value, w_off, w_attn, w_out, w1, w2,
                                           b_off, b_attn, src, pos,
                                           wv_t, woa_t, wout_t, w1_t, w2_t, boa, srcb, qb);
    gemm5<<<dim3(5 * MB), b256, 0, stream>>>(srcb, qb, wv_t, woa_t, b_value, boa, Vh, OA);
    ms_sample<<<dim3(N_TOK / 2), b256, 0, stream>>>(Vh, OA, refp, Sb);
    gemm_ln<<<dim3((N_TOK + 63) / 64), b256, 0, stream>>>(Sb, wout_t, b_out, src,
                                                          ln1_g, ln1_b, X, Xb, N_TOK, 256);
    gemm2<<<dim3(8, MB), b512, 0, stream>>>(Xb, w1_t, b1, Hb, N_TOK, 1024, 256, 1);
    gemm_ln<<<dim3((N_TOK + 63) / 64), b256, 0, stream>>>(Hb, w2_t, b2, X,
                                                          ln2_g, ln2_b, out, nullptr, N_TOK, 1024);
}